// Round 2
// baseline (2003.762 us; speedup 1.0000x reference)
//
#include <hip/hip_runtime.h>
#include <hip/hip_bf16.h>

#define BB   8
#define HH   64
#define WWID 64
#define CC   384
#define FF   1536
#define EE   8
#define LL   256
#define NPIX 32768   // B*H*W tokens (one per pixel)
#define CAP  32768   // max entries per expert
#define TM   64      // tokens per FFN block

typedef unsigned short ushort_t;
typedef __attribute__((ext_vector_type(4))) unsigned short u16x4;
typedef __attribute__((ext_vector_type(8))) short          s16x8;  // 8 bf16 (4 VGPRs) MFMA A/B frag
typedef __attribute__((ext_vector_type(4))) float          f32x4;  // MFMA C/D frag / float4 load

__device__ __forceinline__ ushort_t f2bf(float f) {
  union { float f; unsigned int i; } v; v.f = f;
  unsigned int u = v.i;
  u += 0x7fffu + ((u >> 16) & 1u);   // round-to-nearest-even
  return (ushort_t)(u >> 16);
}

// ---------------------------------------------------------------------------
// Transpose+cast: src f32 [E][R][Cd] -> dst bf16 [E][Cd][R]  (R,Cd mult of 32)
// ---------------------------------------------------------------------------
__global__ __launch_bounds__(256) void k_transpose(const float* __restrict__ src,
                                                   ushort_t* __restrict__ dst,
                                                   int R, int Cd) {
  __shared__ ushort_t tile[32][33];
  int e  = blockIdx.z;
  int c0 = blockIdx.x * 32, r0 = blockIdx.y * 32;
  int tx = threadIdx.x & 31, ty = threadIdx.x >> 5;   // 32 x 8
  const float* s = src + (size_t)e * R * Cd;
  ushort_t*    d = dst + (size_t)e * R * Cd;
  #pragma unroll
  for (int i = 0; i < 32; i += 8)
    tile[ty + i][tx] = f2bf(s[(size_t)(r0 + ty + i) * Cd + c0 + tx]);
  __syncthreads();
  #pragma unroll
  for (int i = 0; i < 32; i += 8)
    d[(size_t)(c0 + ty + i) * R + r0 + tx] = tile[tx][ty + i];
}

// ---------------------------------------------------------------------------
// Router: one block per (b, conv-patch l2). fp32 logits -> softmax -> top2.
// ---------------------------------------------------------------------------
__global__ __launch_bounds__(256) void k_router(const float* __restrict__ x,
                                                const float* __restrict__ gw,
                                                int* __restrict__ re, float* __restrict__ rw) {
  int bid = blockIdx.x;                 // b*256 + l2
  int b = bid >> 8, l2 = bid & 255;
  int hp = l2 >> 4, wp = l2 & 15;
  int t = threadIdx.x;
  int e = t >> 5, lane = t & 31;
  const float* xb = x + (size_t)b * (HH * WWID) * CC;
  const float* ge = gw + (size_t)e * CC * 16;
  float acc = 0.f;
  for (int c = lane; c < CC; c += 32) {
    const float* gp = ge + c * 16;
    #pragma unroll
    for (int kh = 0; kh < 4; ++kh) {
      const float* xr = xb + (size_t)((hp * 4 + kh) * 64 + wp * 4) * CC + c;
      #pragma unroll
      for (int kw = 0; kw < 4; ++kw)
        acc += xr[(size_t)kw * CC] * gp[kh * 4 + kw];
    }
  }
  #pragma unroll
  for (int d = 16; d; d >>= 1) acc += __shfl_down(acc, d, 32);
  __shared__ float logits[EE];
  if (lane == 0) logits[e] = acc;
  __syncthreads();
  if (t == 0) {
    float m = logits[0];
    #pragma unroll
    for (int i = 1; i < EE; ++i) m = fmaxf(m, logits[i]);
    float p[EE]; float s = 0.f;
    #pragma unroll
    for (int i = 0; i < EE; ++i) { p[i] = expf(logits[i] - m); s += p[i]; }
    #pragma unroll
    for (int i = 0; i < EE; ++i) p[i] /= s;
    int e0 = 0;
    #pragma unroll
    for (int i = 1; i < EE; ++i) if (p[i] > p[e0]) e0 = i;
    int e1 = (e0 == 0) ? 1 : 0;
    #pragma unroll
    for (int i = 0; i < EE; ++i) if (i != e0 && p[i] > p[e1]) e1 = i;
    float s2 = p[e0] + p[e1] + 1e-9f;
    re[bid * 2 + 0] = e0;  re[bid * 2 + 1] = e1;
    rw[bid * 2 + 0] = p[e0] / s2;  rw[bid * 2 + 1] = p[e1] / s2;
  }
}

// ---------------------------------------------------------------------------
// Assign: one thread per (patch, slot); emits 16 pixel entries to expert list.
// Token (b,l2,j) carries pixel h=(l2&15)*4+((l2>>4)>>2), w=j*4+((l2>>4)&3),
// routed by conv patch l2. (Scramble derived from U.reshape(B,C,L,k2).)
// ---------------------------------------------------------------------------
__global__ void k_assign(const int* __restrict__ re, const float* __restrict__ rw,
                         int* __restrict__ cnt, int* __restrict__ ids, float* __restrict__ wts) {
  int i = blockIdx.x * blockDim.x + threadIdx.x;   // patch*2 + slot
  if (i >= BB * LL * 2) return;
  int pat = i >> 1, slot = i & 1;
  int b = pat >> 8, l2 = pat & 255;
  int e = re[pat * 2 + slot];
  float w = rw[pat * 2 + slot];
  int t2 = l2 >> 4, hp = l2 & 15;
  int kh = t2 >> 2, kw = t2 & 3;
  int h = hp * 4 + kh;
  int pos = atomicAdd(&cnt[e], 16);
  #pragma unroll
  for (int j = 0; j < 16; ++j) {
    int wpix = j * 4 + kw;
    int pix = (b << 12) + (h << 6) + wpix;
    ids[e * CAP + pos + j] = pix;
    wts[e * CAP + pos + j] = w;
  }
}

// ---------------------------------------------------------------------------
// FFN: grid (512 tiles, 8 experts). 64 tokens/block, 4 waves x 16-row strips.
// MFMA 16x16x32 bf16: A[m=l&15][k=quad*8+j], B[k=quad*8+j][n=l&15],
//                     D[row=quad*4+r][col=l&15].
// ---------------------------------------------------------------------------
__global__ __launch_bounds__(256) void k_ffn(const float* __restrict__ x,
                                             const ushort_t* __restrict__ w1t,  // bf16 [E][F][C]
                                             const float* __restrict__ b1,
                                             const ushort_t* __restrict__ w2t,  // bf16 [E][C][F]
                                             const float* __restrict__ b2,
                                             const int* __restrict__ cnt,
                                             const int* __restrict__ ids,
                                             const float* __restrict__ wts,
                                             float* __restrict__ out_tok) {
  int e = blockIdx.y;
  int tile = blockIdx.x;
  int ne = cnt[e];
  if (tile * TM >= ne) return;

  __shared__ ushort_t xs[TM][CC + 8];    // bf16; +8 pad keeps b128 reads 2-way (free)
  __shared__ ushort_t hb[TM][64 + 8];
  __shared__ int   s_id[TM];
  __shared__ float s_w[TM];

  int t = threadIdx.x;
  if (t < TM) {
    int i = tile * TM + t;
    if (i < ne) { s_id[t] = ids[e * CAP + i]; s_w[t] = wts[e * CAP + i]; }
    else        { s_id[t] = -1;               s_w[t] = 0.f; }
  }
  __syncthreads();

  // gather X rows (f32 float4 loads, cast to bf16 into LDS)
  for (int i = t; i < TM * 96; i += 256) {
    int row = i / 96, ch = (i % 96) * 4;
    int id = s_id[row];
    f32x4 v = (f32x4){0.f, 0.f, 0.f, 0.f};
    if (id >= 0) v = *reinterpret_cast<const f32x4*>(x + (size_t)id * CC + ch);
    u16x4 o = {f2bf(v.x), f2bf(v.y), f2bf(v.z), f2bf(v.w)};
    *reinterpret_cast<u16x4*>(&xs[row][ch]) = o;
  }
  __syncthreads();

  int lane = t & 63;
  int wvid = t >> 6;
  int rb = wvid * 16;
  int l15 = lane & 15, quad = lane >> 4;

  f32x4 yacc[24];
  #pragma unroll
  for (int i = 0; i < 24; ++i) yacc[i] = (f32x4){0.f, 0.f, 0.f, 0.f};

  const ushort_t* w1e = w1t + (size_t)e * FF * CC;
  const ushort_t* w2e = w2t + (size_t)e * CC * FF;

  for (int fc = 0; fc < FF / 64; ++fc) {          // 24 f-chunks
    // ---- GEMM1: H[16][64] = X[16][384] @ W1[:, chunk] + b1 ----
    f32x4 hacc[4];
    #pragma unroll
    for (int nt = 0; nt < 4; ++nt) {
      float bv = b1[e * FF + fc * 64 + nt * 16 + l15];   // bias depends on col only
      hacc[nt] = (f32x4){bv, bv, bv, bv};
    }
    for (int k0 = 0; k0 < CC; k0 += 32) {        // 12 k-steps
      s16x8 a = *reinterpret_cast<const s16x8*>(&xs[rb + l15][k0 + quad * 8]);
      #pragma unroll
      for (int nt = 0; nt < 4; ++nt) {
        const ushort_t* bp = w1e + (size_t)(fc * 64 + nt * 16 + l15) * CC + k0 + quad * 8;
        s16x8 bf = *reinterpret_cast<const s16x8*>(bp);
        hacc[nt] = __builtin_amdgcn_mfma_f32_16x16x32_bf16(a, bf, hacc[nt], 0, 0, 0);
      }
    }
    // ---- gelu (exact) -> per-wave-private hb rows (C-layout -> A-layout) ----
    #pragma unroll
    for (int nt = 0; nt < 4; ++nt)
      #pragma unroll
      for (int r = 0; r < 4; ++r) {
        float v = hacc[nt][r];
        float g = 0.5f * v * (1.f + erff(v * 0.70710678118654752f));
        hb[rb + quad * 4 + r][nt * 16 + l15] = f2bf(g);
      }
    __syncthreads();   // wave-private rows, but keep waves in step (cheap)
    // ---- GEMM2: Y[16][384] += H[16][64] @ W2[chunk, :] ----
    #pragma unroll
    for (int k0 = 0; k0 < 64; k0 += 32) {        // 2 k-steps
      s16x8 a2 = *reinterpret_cast<const s16x8*>(&hb[rb + l15][k0 + quad * 8]);
      #pragma unroll
      for (int nt = 0; nt < 24; ++nt) {
        const ushort_t* bp = w2e + (size_t)(nt * 16 + l15) * FF + fc * 64 + k0 + quad * 8;
        s16x8 bf = *reinterpret_cast<const s16x8*>(bp);
        yacc[nt] = __builtin_amdgcn_mfma_f32_16x16x32_bf16(a2, bf, yacc[nt], 0, 0, 0);
      }
    }
  }

  // ---- epilogue: +b2, * gate weight, scatter-add into token accumulator ----
  #pragma unroll
  for (int nt = 0; nt < 24; ++nt) {
    int c = nt * 16 + l15;
    float b2v = b2[e * CC + c];
    #pragma unroll
    for (int r = 0; r < 4; ++r) {
      int row = rb + quad * 4 + r;
      int id = s_id[row];
      if (id >= 0) {
        float val = (yacc[nt][r] + b2v) * s_w[row];
        atomicAdd(&out_tok[(size_t)id * CC + c], val);
      }
    }
  }
}

// ---------------------------------------------------------------------------
// Finalize: out_tok [pix][C] f32 -> d_out [B][H][C][W] f32 (tile transpose)
// ---------------------------------------------------------------------------
__global__ __launch_bounds__(256) void k_final(const float* __restrict__ out_tok,
                                               float* __restrict__ out) {
  int bid = blockIdx.x;                 // b*64 + h
  __shared__ float tile[64][193];
  int t = threadIdx.x;
  const float* src = out_tok + (size_t)(bid << 6) * CC;      // + w*C + c
  float* dst = out + (size_t)bid * CC * WWID;                // [c][w]
  #pragma unroll
  for (int half = 0; half < 2; ++half) {
    int c0 = half * 192;
    for (int i = t; i < 64 * 192; i += 256) {
      int w = i / 192, cl = i % 192;
      tile[w][cl] = src[(size_t)w * CC + c0 + cl];
    }
    __syncthreads();
    for (int i = t; i < 64 * 192; i += 256) {
      int cl = i / 64, w = i % 64;
      dst[(size_t)(c0 + cl) * WWID + w] = tile[w][cl];
    }
    __syncthreads();
  }
}

// ---------------------------------------------------------------------------
extern "C" void kernel_launch(void* const* d_in, const int* in_sizes, int n_in,
                              void* d_out, int out_size, void* d_ws, size_t ws_size,
                              hipStream_t stream) {
  const float* x  = (const float*)d_in[0];
  const float* gw = (const float*)d_in[1];
  const float* w1 = (const float*)d_in[2];
  const float* b1 = (const float*)d_in[3];
  const float* w2 = (const float*)d_in[4];
  const float* b2 = (const float*)d_in[5];

  char* ws = (char*)d_ws;
  size_t off = 0;
  float* out_tok = (float*)(ws + off); off += (size_t)NPIX * CC * 4;   // 50,331,648
  int*   cnt     = (int*)(ws + off);   off += 256;
  int*   ids     = (int*)(ws + off);   off += (size_t)EE * CAP * 4;
  float* wts     = (float*)(ws + off); off += (size_t)EE * CAP * 4;
  int*   re      = (int*)(ws + off);   off += (size_t)BB * LL * 2 * 4;
  float* rw      = (float*)(ws + off); off += (size_t)BB * LL * 2 * 4;
  ushort_t* w1t  = (ushort_t*)(ws + off); off += (size_t)EE * FF * CC * 2;
  ushort_t* w2t  = (ushort_t*)(ws + off); off += (size_t)EE * FF * CC * 2;

  // zero token accumulator + expert counters (contiguous)
  hipMemsetAsync(out_tok, 0, (size_t)NPIX * CC * 4 + 256, stream);

  k_transpose<<<dim3(FF / 32, CC / 32, EE), 256, 0, stream>>>(w1, w1t, CC, FF); // -> [E][F][C]
  k_transpose<<<dim3(CC / 32, FF / 32, EE), 256, 0, stream>>>(w2, w2t, FF, CC); // -> [E][C][F]
  k_router<<<BB * LL, 256, 0, stream>>>(x, gw, re, rw);
  k_assign<<<16, 256, 0, stream>>>(re, rw, cnt, ids, wts);
  k_ffn<<<dim3(CAP / TM, EE), 256, 0, stream>>>(x, w1t, b1, w2t, b2, cnt, ids, wts, out_tok);
  k_final<<<BB * HH, 256, 0, stream>>>(out_tok, (float*)d_out);
}

// Round 4
// 757.455 us; speedup vs baseline: 2.6454x; 2.6454x over previous
//
#include <hip/hip_runtime.h>
#include <hip/hip_bf16.h>

#define BB   8
#define HH   64
#define WWID 64
#define CC   384
#define FF   1536
#define EE   8
#define LL   256
#define MTOTMAX 66560   // 65536 real rows + 8*128 max padding
#define NTMAX   520     // MTOTMAX/128

typedef unsigned short ushort_t;
typedef __attribute__((ext_vector_type(4))) unsigned short u16x4;
typedef __attribute__((ext_vector_type(8))) short          s16x8;  // 8 bf16 MFMA A/B frag
typedef __attribute__((ext_vector_type(4))) float          f32x4;  // MFMA C/D frag / float4

__device__ __forceinline__ float bf2f(ushort_t u) {
  union { unsigned int i; float f; } v; v.i = ((unsigned int)u) << 16; return v.f;
}
__device__ __forceinline__ ushort_t f2bf(float f) {
  union { float f; unsigned int i; } v; v.f = f;
  unsigned int u = v.i;
  u += 0x7fffu + ((u >> 16) & 1u);
  return (ushort_t)(u >> 16);
}
// gelu exact via A&S 7.1.26 erf (|err|~1.5e-7 << bf16 rounding)
__device__ __forceinline__ float gelu_f(float x) {
  float u  = 0.70710678118654752f * x;
  float au = fabsf(u);
  float t  = 1.0f / (1.0f + 0.3275911f * au);
  float poly = t * (0.254829592f + t * (-0.284496736f + t * (1.421413741f +
               t * (-1.453152027f + t * 1.061405429f))));
  float ea = 1.0f - poly * __expf(-au * au);
  float erfv = (x < 0.f) ? -ea : ea;
  return 0.5f * x * (1.0f + erfv);
}

// async 16B/lane global->LDS; LDS dest = wave-uniform base + lane*16
#define GLDS(g, l) __builtin_amdgcn_global_load_lds( \
    (const __attribute__((address_space(1))) void*)(g), \
    (__attribute__((address_space(3))) void*)(l), 16, 0, 0)

// ---------------------------------------------------------------------------
// Transpose+cast: src f32 [E][R][Cd] -> dst bf16 [E][Cd][R]
// ---------------------------------------------------------------------------
__global__ __launch_bounds__(256) void k_transpose(const float* __restrict__ src,
                                                   ushort_t* __restrict__ dst,
                                                   int R, int Cd) {
  __shared__ ushort_t tile[32][33];
  int e  = blockIdx.z;
  int c0 = blockIdx.x * 32, r0 = blockIdx.y * 32;
  int tx = threadIdx.x & 31, ty = threadIdx.x >> 5;
  const float* s = src + (size_t)e * R * Cd;
  ushort_t*    d = dst + (size_t)e * R * Cd;
  #pragma unroll
  for (int i = 0; i < 32; i += 8)
    tile[ty + i][tx] = f2bf(s[(size_t)(r0 + ty + i) * Cd + c0 + tx]);
  __syncthreads();
  #pragma unroll
  for (int i = 0; i < 32; i += 8)
    d[(size_t)(c0 + ty + i) * R + r0 + tx] = tile[tx][ty + i];
}

// ---------------------------------------------------------------------------
// Router: one block per (b, conv-patch l2). fp32 logits -> softmax -> top2.
// ---------------------------------------------------------------------------
__global__ __launch_bounds__(256) void k_router(const float* __restrict__ x,
                                                const float* __restrict__ gw,
                                                int* __restrict__ re, float* __restrict__ rw) {
  int bid = blockIdx.x;                 // b*256 + l2
  int b = bid >> 8, l2 = bid & 255;
  int hp = l2 >> 4, wp = l2 & 15;
  int t = threadIdx.x;
  int e = t >> 5, lane = t & 31;
  const float* xb = x + (size_t)b * (HH * WWID) * CC;
  const float* ge = gw + (size_t)e * CC * 16;
  float acc = 0.f;
  for (int c = lane; c < CC; c += 32) {
    const float* gp = ge + c * 16;
    #pragma unroll
    for (int kh = 0; kh < 4; ++kh) {
      const float* xr = xb + (size_t)((hp * 4 + kh) * 64 + wp * 4) * CC + c;
      #pragma unroll
      for (int kw = 0; kw < 4; ++kw)
        acc += xr[(size_t)kw * CC] * gp[kh * 4 + kw];
    }
  }
  #pragma unroll
  for (int d = 16; d; d >>= 1) acc += __shfl_down(acc, d, 32);
  __shared__ float logits[EE];
  if (lane == 0) logits[e] = acc;
  __syncthreads();
  if (t == 0) {
    float m = logits[0];
    #pragma unroll
    for (int i = 1; i < EE; ++i) m = fmaxf(m, logits[i]);
    float p[EE]; float s = 0.f;
    #pragma unroll
    for (int i = 0; i < EE; ++i) { p[i] = __expf(logits[i] - m); s += p[i]; }
    #pragma unroll
    for (int i = 0; i < EE; ++i) p[i] /= s;
    int e0 = 0;
    #pragma unroll
    for (int i = 1; i < EE; ++i) if (p[i] > p[e0]) e0 = i;
    int e1 = (e0 == 0) ? 1 : 0;
    #pragma unroll
    for (int i = 0; i < EE; ++i) if (i != e0 && p[i] > p[e1]) e1 = i;
    float s2 = p[e0] + p[e1] + 1e-9f;
    re[bid * 2 + 0] = e0;  re[bid * 2 + 1] = e1;
    rw[bid * 2 + 0] = p[e0] / s2;  rw[bid * 2 + 1] = p[e1] / s2;
  }
}

// ---------------------------------------------------------------------------
// Count: 16 rows per (patch,slot) into cnt[e]
// ---------------------------------------------------------------------------
__global__ void k_count(const int* __restrict__ re, int* __restrict__ cnt) {
  int i = blockIdx.x * blockDim.x + threadIdx.x;
  if (i >= BB * LL * 2) return;
  atomicAdd(&cnt[re[i]], 16);
}

// ---------------------------------------------------------------------------
// Pad/prefix: cntp=round128(cnt), basep prefix, tile2e, pad gids. One block.
// ---------------------------------------------------------------------------
__global__ void k_pad(const int* __restrict__ cnt, int* __restrict__ cntp,
                      int* __restrict__ basep, int* __restrict__ tile2e,
                      int* __restrict__ gids, float* __restrict__ gwts) {
  __shared__ int s_cnt[EE], s_cntp[EE], s_base[EE];
  int t = threadIdx.x;
  if (t == 0) {
    int b = 0;
    for (int e = 0; e < EE; ++e) {
      int c  = cnt[e];
      int cp = (c + 127) & ~127;
      s_cnt[e] = c; s_cntp[e] = cp; s_base[e] = b;
      cntp[e] = cp; basep[e] = b;
      for (int g = b >> 7; g < (b + cp) >> 7; ++g) tile2e[g] = e;
      b += cp;
    }
    basep[EE] = b;
  }
  __syncthreads();
  for (int e = 0; e < EE; ++e)
    for (int i = s_cnt[e] + t; i < s_cntp[e]; i += blockDim.x) {
      gids[s_base[e] + i] = -1;
      gwts[s_base[e] + i] = 0.f;
    }
}

// ---------------------------------------------------------------------------
// Assign: one thread per (patch,slot); 16 pixel rows into compacted gids/gwts.
// id=(slot<<15)|pix; pix=b*4096+h*64+w; h=(l2&15)*4+((l2>>4)>>2),
// w=j*4+((l2>>4)&3)  (scramble from reference's U.reshape(B,C,L,k2)).
// ---------------------------------------------------------------------------
__global__ void k_assign(const int* __restrict__ re, const float* __restrict__ rw,
                         const int* __restrict__ basep, int* __restrict__ cnt2,
                         int* __restrict__ gids, float* __restrict__ gwts) {
  int i = blockIdx.x * blockDim.x + threadIdx.x;   // patch*2 + slot
  if (i >= BB * LL * 2) return;
  int pat = i >> 1, slot = i & 1;
  int b = pat >> 8, l2 = pat & 255;
  int e = re[i];
  float w = rw[i];
  int t2 = l2 >> 4, hp = l2 & 15;
  int kh = t2 >> 2, kw = t2 & 3;
  int h = hp * 4 + kh;
  int row = basep[e] + atomicAdd(&cnt2[e], 16);
  #pragma unroll
  for (int j = 0; j < 16; ++j) {
    int wpix = j * 4 + kw;
    int pix = (b << 12) + (h << 6) + wpix;
    gids[row + j] = (slot << 15) | pix;
    gwts[row + j] = w;
  }
}

// ---------------------------------------------------------------------------
// Gather chunk: x f32 rows -> Xc bf16 [local row][CC]; global tile = t0+bx.
// ---------------------------------------------------------------------------
__global__ __launch_bounds__(256) void k_gather(const float* __restrict__ x,
                                                const int* __restrict__ gids,
                                                const int* __restrict__ basep,
                                                ushort_t* __restrict__ Xc, int t0) {
  int g = t0 + blockIdx.x;
  if (g * 128 >= basep[EE]) return;
  __shared__ int s_id[128];
  int t = threadIdx.x;
  if (t < 128) s_id[t] = gids[g * 128 + t];
  __syncthreads();
  ushort_t* dst = Xc + (size_t)blockIdx.x * 128 * CC;
  for (int i = t; i < 128 * 96; i += 256) {
    int row = i / 96, ch = (i % 96) * 4;
    int id = s_id[row];
    f32x4 v = (f32x4){0.f, 0.f, 0.f, 0.f};
    if (id >= 0) v = *reinterpret_cast<const f32x4*>(x + (size_t)(id & 32767) * CC + ch);
    u16x4 o = {f2bf(v.x), f2bf(v.y), f2bf(v.z), f2bf(v.w)};
    *reinterpret_cast<u16x4*>(dst + (size_t)row * CC + ch) = o;
  }
}

// ---------------------------------------------------------------------------
// GEMM1: Hc[m][1536] = gelu(Xc[m][384] @ W1t^T + b1).  128x128 tile, BK=32.
// LDS: 8 chunks of 1KB per operand; chunk = 16x32 MFMA tile stored frag-major
// so frag read = ds_read_b128 at chunk+lane*16 (conflict-free); GLDS deposits
// lane*16 contiguous (stage lane q*16+l15 -> row l15, k-sub q).
// ---------------------------------------------------------------------------
__global__ __launch_bounds__(256, 4) void k_gemm1(const ushort_t* __restrict__ Xc,
                                                  const ushort_t* __restrict__ w1t,
                                                  const float* __restrict__ b1,
                                                  const int* __restrict__ basep,
                                                  const int* __restrict__ tile2e,
                                                  ushort_t* __restrict__ Hc, int t0) {
  int g = t0 + blockIdx.y;
  if (g * 128 >= basep[EE]) return;
  int e = tile2e[g], nb = blockIdx.x;
  __shared__ ushort_t As[4096];   // 8 x (16m x 32k) chunks
  __shared__ ushort_t Bs[4096];
  int t = threadIdx.x, w = t >> 6, lane = t & 63;
  int l15 = lane & 15, q = lane >> 4;
  const ushort_t* a_src = Xc + (size_t)blockIdx.y * 128 * CC;
  const ushort_t* b_src = w1t + ((size_t)e * FF + nb * 128) * CC;
  int mh = (w & 1) * 4, nh = (w >> 1) * 4;   // per-wave 64x64 sub-tile
  f32x4 acc[4][4];
  #pragma unroll
  for (int i = 0; i < 4; ++i)
    #pragma unroll
    for (int j = 0; j < 4; ++j) acc[i][j] = (f32x4){0.f, 0.f, 0.f, 0.f};

  for (int k0 = 0; k0 < CC; k0 += 32) {
    __syncthreads();
    #pragma unroll
    for (int c = 0; c < 2; ++c) {
      int ch = w * 2 + c;
      GLDS(a_src + (size_t)(ch * 16 + l15) * CC + k0 + q * 8, As + ch * 512);
      GLDS(b_src + (size_t)(ch * 16 + l15) * CC + k0 + q * 8, Bs + ch * 512);
    }
    __syncthreads();
    s16x8 af[4], bf[4];
    #pragma unroll
    for (int i = 0; i < 4; ++i)
      af[i] = *reinterpret_cast<const s16x8*>(As + (mh + i) * 512 + lane * 8);
    #pragma unroll
    for (int j = 0; j < 4; ++j)
      bf[j] = *reinterpret_cast<const s16x8*>(Bs + (nh + j) * 512 + lane * 8);
    #pragma unroll
    for (int i = 0; i < 4; ++i)
      #pragma unroll
      for (int j = 0; j < 4; ++j)
        acc[i][j] = __builtin_amdgcn_mfma_f32_16x16x32_bf16(af[i], bf[j], acc[i][j], 0, 0, 0);
  }

  ushort_t* hrow = Hc + (size_t)blockIdx.y * 128 * FF + nb * 128;
  #pragma unroll
  for (int j = 0; j < 4; ++j) {
    int col = (nh + j) * 16 + l15;
    float bj = b1[e * FF + nb * 128 + col];
    #pragma unroll
    for (int i = 0; i < 4; ++i)
      #pragma unroll
      for (int r = 0; r < 4; ++r) {
        int m = (mh + i) * 16 + q * 4 + r;
        hrow[(size_t)m * FF + col] = f2bf(gelu_f(acc[i][j][r] + bj));
      }
  }
}

// ---------------------------------------------------------------------------
// GEMM2: y[id][384] = (Hc[m][1536] @ W2t^T + b2) * gate_w.  Same structure.
// ---------------------------------------------------------------------------
__global__ __launch_bounds__(256, 4) void k_gemm2(const ushort_t* __restrict__ Hc,
                                                  const ushort_t* __restrict__ w2t,
                                                  const float* __restrict__ b2,
                                                  const int* __restrict__ basep,
                                                  const int* __restrict__ tile2e,
                                                  const int* __restrict__ gids,
                                                  const float* __restrict__ gwts,
                                                  ushort_t* __restrict__ y, int t0) {
  int g = t0 + blockIdx.y;
  if (g * 128 >= basep[EE]) return;
  int e = tile2e[g], nb = blockIdx.x;
  __shared__ ushort_t As[4096];
  __shared__ ushort_t Bs[4096];
  __shared__ int   s_id[128];
  __shared__ float s_w[128];
  int t = threadIdx.x, w = t >> 6, lane = t & 63;
  int l15 = lane & 15, q = lane >> 4;
  if (t < 128) {
    s_id[t] = gids[g * 128 + t];
    s_w[t]  = gwts[g * 128 + t];
  }
  const ushort_t* a_src = Hc + (size_t)blockIdx.y * 128 * FF;
  const ushort_t* b_src = w2t + ((size_t)e * CC + nb * 128) * FF;
  int mh = (w & 1) * 4, nh = (w >> 1) * 4;
  f32x4 acc[4][4];
  #pragma unroll
  for (int i = 0; i < 4; ++i)
    #pragma unroll
    for (int j = 0; j < 4; ++j) acc[i][j] = (f32x4){0.f, 0.f, 0.f, 0.f};

  for (int k0 = 0; k0 < FF; k0 += 32) {
    __syncthreads();
    #pragma unroll
    for (int c = 0; c < 2; ++c) {
      int ch = w * 2 + c;
      GLDS(a_src + (size_t)(ch * 16 + l15) * FF + k0 + q * 8, As + ch * 512);
      GLDS(b_src + (size_t)(ch * 16 + l15) * FF + k0 + q * 8, Bs + ch * 512);
    }
    __syncthreads();
    s16x8 af[4], bf[4];
    #pragma unroll
    for (int i = 0; i < 4; ++i)
      af[i] = *reinterpret_cast<const s16x8*>(As + (mh + i) * 512 + lane * 8);
    #pragma unroll
    for (int j = 0; j < 4; ++j)
      bf[j] = *reinterpret_cast<const s16x8*>(Bs + (nh + j) * 512 + lane * 8);
    #pragma unroll
    for (int i = 0; i < 4; ++i)
      #pragma unroll
      for (int j = 0; j < 4; ++j)
        acc[i][j] = __builtin_amdgcn_mfma_f32_16x16x32_bf16(af[i], bf[j], acc[i][j], 0, 0, 0);
  }

  #pragma unroll
  for (int j = 0; j < 4; ++j) {
    int col = nb * 128 + (nh + j) * 16 + l15;
    float bj = b2[e * CC + col];
    #pragma unroll
    for (int i = 0; i < 4; ++i)
      #pragma unroll
      for (int r = 0; r < 4; ++r) {
        int m = (mh + i) * 16 + q * 4 + r;
        int id = s_id[m];
        if (id >= 0)
          y[(size_t)id * CC + col] = f2bf((acc[i][j][r] + bj) * s_w[m]);
      }
  }
}

// ---------------------------------------------------------------------------
// Finalize: out[b][h][c][w] = y[pix] + y[32768+pix]  (bf16 -> f32, transpose)
// ---------------------------------------------------------------------------
__global__ __launch_bounds__(256) void k_final(const ushort_t* __restrict__ y,
                                               float* __restrict__ out) {
  int bid = blockIdx.x;                 // b*64 + h
  __shared__ float tile[64][193];
  int t = threadIdx.x;
  float* dst = out + (size_t)bid * CC * WWID;   // [c][w]
  #pragma unroll
  for (int half = 0; half < 2; ++half) {
    int c0 = half * 192;
    for (int i = t; i < 64 * 48; i += 256) {
      int w = i / 48, c4 = (i % 48) * 4;
      int pix = (bid << 6) + w;
      u16x4 a = *reinterpret_cast<const u16x4*>(y + (size_t)pix * CC + c0 + c4);
      u16x4 b = *reinterpret_cast<const u16x4*>(y + (size_t)(32768 + pix) * CC + c0 + c4);
      #pragma unroll
      for (int k = 0; k < 4; ++k)
        tile[w][c4 + k] = bf2f(a[k]) + bf2f(b[k]);
    }
    __syncthreads();
    for (int i = t; i < 64 * 192; i += 256) {
      int cl = i / 64, w = i % 64;
      dst[(size_t)(c0 + cl) * WWID + w] = tile[w][cl];
    }
    __syncthreads();
  }
}

// ---------------------------------------------------------------------------
extern "C" void kernel_launch(void* const* d_in, const int* in_sizes, int n_in,
                              void* d_out, int out_size, void* d_ws, size_t ws_size,
                              hipStream_t stream) {
  const float* x  = (const float*)d_in[0];
  const float* gw = (const float*)d_in[1];
  const float* w1 = (const float*)d_in[2];
  const float* b1 = (const float*)d_in[3];
  const float* w2 = (const float*)d_in[4];
  const float* b2 = (const float*)d_in[5];

  // fixed footprint (bytes): w1t+w2t+y+gids+gwts+re+rw+tile2e+counters
  const size_t fixed = (size_t)EE * FF * CC * 2 * 2   // w1t, w2t   18,874,368
                     + (size_t)65536 * CC * 2          // y          50,331,648
                     + (size_t)MTOTMAX * 4 * 2         // gids,gwts     532,480
                     + (size_t)BB * LL * 2 * 4 * 2     // re, rw         32,768
                     + (size_t)NTMAX * 4               // tile2e          2,080
                     + 1024;                           // counters + slack
  // pick largest M-chunk whose Xc (MC*768B) + Hc (MC*3072B) fits
  const int cands[7] = {66560, 32768, 16384, 8192, 4096, 2048, 1024};
  int MC = 1024;
  for (int i = 0; i < 7; ++i)
    if (fixed + (size_t)cands[i] * 3840 <= ws_size) { MC = cands[i]; break; }
  const int npass = (MTOTMAX + MC - 1) / MC;
  const int ntile = MC / 128;

  char* ws = (char*)d_ws;
  size_t off = 0;
  ushort_t* Xc   = (ushort_t*)(ws + off); off += (size_t)MC * CC * 2;
  ushort_t* Hc   = (ushort_t*)(ws + off); off += (size_t)MC * FF * 2;
  ushort_t* w1t  = (ushort_t*)(ws + off); off += (size_t)EE * FF * CC * 2;
  ushort_t* w2t  = (ushort_t*)(ws + off); off += (size_t)EE * FF * CC * 2;
  ushort_t* y    = (ushort_t*)(ws + off); off += (size_t)65536 * CC * 2;
  int*   gids  = (int*)(ws + off);   off += (size_t)MTOTMAX * 4;
  float* gwts  = (float*)(ws + off); off += (size_t)MTOTMAX * 4;
  int*   re    = (int*)(ws + off);   off += (size_t)BB * LL * 2 * 4;
  float* rw    = (float*)(ws + off); off += (size_t)BB * LL * 2 * 4;
  int*   tile2e= (int*)(ws + off);   off += (size_t)NTMAX * 4;
  int*   cnt   = (int*)(ws + off);   off += 64;
  int*   cnt2  = (int*)(ws + off);   off += 64;
  int*   cntp  = (int*)(ws + off);   off += 64;
  int*   basep = (int*)(ws + off);   off += 64;

  hipMemsetAsync(cnt, 0, 128, stream);   // cnt + cnt2

  k_transpose<<<dim3(FF / 32, CC / 32, EE), 256, 0, stream>>>(w1, w1t, CC, FF); // [E][F][C]
  k_transpose<<<dim3(CC / 32, FF / 32, EE), 256, 0, stream>>>(w2, w2t, FF, CC); // [E][C][F]
  k_router<<<BB * LL, 256, 0, stream>>>(x, gw, re, rw);
  k_count<<<16, 256, 0, stream>>>(re, cnt);
  k_pad<<<1, 256, 0, stream>>>(cnt, cntp, basep, tile2e, gids, gwts);
  k_assign<<<16, 256, 0, stream>>>(re, rw, basep, cnt2, gids, gwts);

  for (int p = 0; p < npass; ++p) {
    int t0 = p * ntile;
    k_gather<<<ntile, 256, 0, stream>>>(x, gids, basep, Xc, t0);
    k_gemm1<<<dim3(FF / 128, ntile), 256, 0, stream>>>(Xc, w1t, b1, basep, tile2e, Hc, t0);
    k_gemm2<<<dim3(CC / 128, ntile), 256, 0, stream>>>(Hc, w2t, b2, basep, tile2e, gids, gwts, y, t0);
  }
  k_final<<<BB * HH, 256, 0, stream>>>(y, (float*)d_out);
}

// Round 5
// 705.309 us; speedup vs baseline: 2.8410x; 1.0739x over previous
//
#include <hip/hip_runtime.h>
#include <hip/hip_bf16.h>

#define BB   8
#define HH   64
#define WWID 64
#define CC   384
#define FF   1536
#define EE   8
#define LL   256
#define MTOTMAX 66560   // 65536 real rows + 8*128 max padding
#define NTMAX   520     // MTOTMAX/128

typedef unsigned short ushort_t;
typedef __attribute__((ext_vector_type(4))) unsigned short u16x4;
typedef __attribute__((ext_vector_type(8))) short          s16x8;  // 8 bf16 = 16B
typedef __attribute__((ext_vector_type(4))) float          f32x4;

__device__ __forceinline__ float bf2f(ushort_t u) {
  union { unsigned int i; float f; } v; v.i = ((unsigned int)u) << 16; return v.f;
}
__device__ __forceinline__ ushort_t f2bf(float f) {
  union { float f; unsigned int i; } v; v.f = f;
  unsigned int u = v.i;
  u += 0x7fffu + ((u >> 16) & 1u);
  return (ushort_t)(u >> 16);
}
// gelu exact via A&S 7.1.26 erf (|err|~1.5e-7 << bf16 rounding)
__device__ __forceinline__ float gelu_f(float x) {
  float u  = 0.70710678118654752f * x;
  float au = fabsf(u);
  float t  = 1.0f / (1.0f + 0.3275911f * au);
  float poly = t * (0.254829592f + t * (-0.284496736f + t * (1.421413741f +
               t * (-1.453152027f + t * 1.061405429f))));
  float ea = 1.0f - poly * __expf(-au * au);
  float erfv = (x < 0.f) ? -ea : ea;
  return 0.5f * x * (1.0f + erfv);
}

// async 16B/lane global->LDS; LDS dest = wave-uniform base + lane*16
#define GLDS(g, l) __builtin_amdgcn_global_load_lds( \
    (const __attribute__((address_space(1))) void*)(g), \
    (__attribute__((address_space(3))) void*)(l), 16, 0, 0)

// ---------------------------------------------------------------------------
// Transpose+cast: src f32 [E][R][Cd] -> dst bf16 [E][Cd][R]
// ---------------------------------------------------------------------------
__global__ __launch_bounds__(256) void k_transpose(const float* __restrict__ src,
                                                   ushort_t* __restrict__ dst,
                                                   int R, int Cd) {
  __shared__ ushort_t tile[32][33];
  int e  = blockIdx.z;
  int c0 = blockIdx.x * 32, r0 = blockIdx.y * 32;
  int tx = threadIdx.x & 31, ty = threadIdx.x >> 5;
  const float* s = src + (size_t)e * R * Cd;
  ushort_t*    d = dst + (size_t)e * R * Cd;
  #pragma unroll
  for (int i = 0; i < 32; i += 8)
    tile[ty + i][tx] = f2bf(s[(size_t)(r0 + ty + i) * Cd + c0 + tx]);
  __syncthreads();
  #pragma unroll
  for (int i = 0; i < 32; i += 8)
    d[(size_t)(c0 + ty + i) * R + r0 + tx] = tile[tx][ty + i];
}

// ---------------------------------------------------------------------------
// Router: one block per (b, conv-patch l2). fp32 logits -> softmax -> top2.
// Also accumulates per-expert row counts (16 rows per (patch,slot)).
// ---------------------------------------------------------------------------
__global__ __launch_bounds__(256) void k_router(const float* __restrict__ x,
                                                const float* __restrict__ gw,
                                                int* __restrict__ re, float* __restrict__ rw,
                                                int* __restrict__ cnt) {
  int bid = blockIdx.x;                 // b*256 + l2
  int b = bid >> 8, l2 = bid & 255;
  int hp = l2 >> 4, wp = l2 & 15;
  int t = threadIdx.x;
  int e = t >> 5, lane = t & 31;
  const float* xb = x + (size_t)b * (HH * WWID) * CC;
  const float* ge = gw + (size_t)e * CC * 16;
  float acc = 0.f;
  for (int c = lane; c < CC; c += 32) {
    const float* gp = ge + c * 16;
    #pragma unroll
    for (int kh = 0; kh < 4; ++kh) {
      const float* xr = xb + (size_t)((hp * 4 + kh) * 64 + wp * 4) * CC + c;
      #pragma unroll
      for (int kw = 0; kw < 4; ++kw)
        acc += xr[(size_t)kw * CC] * gp[kh * 4 + kw];
    }
  }
  #pragma unroll
  for (int d = 16; d; d >>= 1) acc += __shfl_down(acc, d, 32);
  __shared__ float logits[EE];
  if (lane == 0) logits[e] = acc;
  __syncthreads();
  if (t == 0) {
    float m = logits[0];
    #pragma unroll
    for (int i = 1; i < EE; ++i) m = fmaxf(m, logits[i]);
    float p[EE]; float s = 0.f;
    #pragma unroll
    for (int i = 0; i < EE; ++i) { p[i] = __expf(logits[i] - m); s += p[i]; }
    #pragma unroll
    for (int i = 0; i < EE; ++i) p[i] /= s;
    int e0 = 0;
    #pragma unroll
    for (int i = 1; i < EE; ++i) if (p[i] > p[e0]) e0 = i;
    int e1 = (e0 == 0) ? 1 : 0;
    #pragma unroll
    for (int i = 0; i < EE; ++i) if (i != e0 && p[i] > p[e1]) e1 = i;
    float s2 = p[e0] + p[e1] + 1e-9f;
    re[bid * 2 + 0] = e0;  re[bid * 2 + 1] = e1;
    rw[bid * 2 + 0] = p[e0] / s2;  rw[bid * 2 + 1] = p[e1] / s2;
    atomicAdd(&cnt[e0], 16);
    atomicAdd(&cnt[e1], 16);
  }
}

// ---------------------------------------------------------------------------
// Pad/prefix (PARALLEL): thread0 computes 8-entry prefix in LDS; all threads
// fill cntp/basep/tile2e and the -1 padding.  One block.
// ---------------------------------------------------------------------------
__global__ void k_pad(const int* __restrict__ cnt, int* __restrict__ cntp,
                      int* __restrict__ basep, int* __restrict__ tile2e,
                      int* __restrict__ gids, float* __restrict__ gwts) {
  __shared__ int s_cnt[EE], s_cntp[EE], s_base[EE + 1];
  int t = threadIdx.x;
  if (t == 0) {
    int b = 0;
    for (int e = 0; e < EE; ++e) {
      int c  = cnt[e];
      int cp = (c + 127) & ~127;
      s_cnt[e] = c; s_cntp[e] = cp; s_base[e] = b;
      b += cp;
    }
    s_base[EE] = b;
  }
  __syncthreads();
  if (t < EE) { cntp[t] = s_cntp[t]; basep[t] = s_base[t]; }
  if (t == EE) basep[EE] = s_base[EE];
  int ntot = s_base[EE] >> 7;
  for (int g = t; g < ntot; g += 256) {
    int e = 0;
    #pragma unroll
    for (int i = 1; i < EE; ++i) if (g * 128 >= s_base[i]) e = i;
    tile2e[g] = e;
  }
  for (int e = 0; e < EE; ++e)
    for (int i = s_cnt[e] + t; i < s_cntp[e]; i += 256) {
      gids[s_base[e] + i] = -1;
      gwts[s_base[e] + i] = 0.f;
    }
}

// ---------------------------------------------------------------------------
// Assign: one thread per (patch,slot); 16 pixel rows into compacted gids/gwts.
// id=(slot<<15)|pix; pix=b*4096+h*64+w; h=(l2&15)*4+((l2>>4)>>2),
// w=j*4+((l2>>4)&3)  (scramble from reference's U.reshape(B,C,L,k2)).
// ---------------------------------------------------------------------------
__global__ void k_assign(const int* __restrict__ re, const float* __restrict__ rw,
                         const int* __restrict__ basep, int* __restrict__ cnt2,
                         int* __restrict__ gids, float* __restrict__ gwts) {
  int i = blockIdx.x * blockDim.x + threadIdx.x;   // patch*2 + slot
  if (i >= BB * LL * 2) return;
  int pat = i >> 1, slot = i & 1;
  int b = pat >> 8, l2 = pat & 255;
  int e = re[i];
  float w = rw[i];
  int t2 = l2 >> 4, hp = l2 & 15;
  int kh = t2 >> 2, kw = t2 & 3;
  int h = hp * 4 + kh;
  int row = basep[e] + atomicAdd(&cnt2[e], 16);
  #pragma unroll
  for (int j = 0; j < 16; ++j) {
    int wpix = j * 4 + kw;
    int pix = (b << 12) + (h << 6) + wpix;
    gids[row + j] = (slot << 15) | pix;
    gwts[row + j] = w;
  }
}

// ---------------------------------------------------------------------------
// Gather chunk: x f32 rows -> Xc bf16 [local row][CC]; global tile = t0+bx.
// ---------------------------------------------------------------------------
__global__ __launch_bounds__(256) void k_gather(const float* __restrict__ x,
                                                const int* __restrict__ gids,
                                                const int* __restrict__ basep,
                                                ushort_t* __restrict__ Xc, int t0) {
  int g = t0 + blockIdx.x;
  if (g * 128 >= basep[EE]) return;
  __shared__ int s_id[128];
  int t = threadIdx.x;
  if (t < 128) s_id[t] = gids[g * 128 + t];
  __syncthreads();
  ushort_t* dst = Xc + (size_t)blockIdx.x * 128 * CC;
  for (int i = t; i < 128 * 96; i += 256) {
    int row = i / 96, ch = (i % 96) * 4;
    int id = s_id[row];
    f32x4 v = (f32x4){0.f, 0.f, 0.f, 0.f};
    if (id >= 0) v = *reinterpret_cast<const f32x4*>(x + (size_t)(id & 32767) * CC + ch);
    u16x4 o = {f2bf(v.x), f2bf(v.y), f2bf(v.z), f2bf(v.w)};
    *reinterpret_cast<u16x4*>(dst + (size_t)row * CC + ch) = o;
  }
}

// ---------------------------------------------------------------------------
// GEMM1: Hc[m][1536] = gelu(Xc[m][384] @ W1t^T + b1).  128x128 tile, BK=32.
// LDS: 8 chunks of 1KB per operand; chunk = 16x32 MFMA tile stored frag-major
// (frag read = ds_read_b128 at chunk+lane*16, conflict-free).
// Epilogue: per-wave LDS transpose -> dense 16B global stores.
// ---------------------------------------------------------------------------
__global__ __launch_bounds__(256, 4) void k_gemm1(const ushort_t* __restrict__ Xc,
                                                  const ushort_t* __restrict__ w1t,
                                                  const float* __restrict__ b1,
                                                  const int* __restrict__ basep,
                                                  const int* __restrict__ tile2e,
                                                  ushort_t* __restrict__ Hc, int t0) {
  int g = t0 + blockIdx.y;
  if (g * 128 >= basep[EE]) return;
  int e = tile2e[g], nb = blockIdx.x;
  __shared__ ushort_t As[4096];   // 8 x (16m x 32k) chunks
  __shared__ ushort_t Bs[4096];
  __shared__ ushort_t tbuf[4][64 * 34];   // per-wave transpose buffer (64m x 32f, pad 2)
  int t = threadIdx.x, w = t >> 6, lane = t & 63;
  int l15 = lane & 15, q = lane >> 4;
  const ushort_t* a_src = Xc + (size_t)blockIdx.y * 128 * CC;
  const ushort_t* b_src = w1t + ((size_t)e * FF + nb * 128) * CC;
  int mh = (w & 1) * 4, nh = (w >> 1) * 4;   // per-wave 64x64 sub-tile
  f32x4 acc[4][4];
  #pragma unroll
  for (int i = 0; i < 4; ++i)
    #pragma unroll
    for (int j = 0; j < 4; ++j) acc[i][j] = (f32x4){0.f, 0.f, 0.f, 0.f};

  for (int k0 = 0; k0 < CC; k0 += 32) {
    __syncthreads();
    #pragma unroll
    for (int c = 0; c < 2; ++c) {
      int ch = w * 2 + c;
      GLDS(a_src + (size_t)(ch * 16 + l15) * CC + k0 + q * 8, As + ch * 512);
      GLDS(b_src + (size_t)(ch * 16 + l15) * CC + k0 + q * 8, Bs + ch * 512);
    }
    __syncthreads();
    s16x8 af[4], bf[4];
    #pragma unroll
    for (int i = 0; i < 4; ++i)
      af[i] = *reinterpret_cast<const s16x8*>(As + (mh + i) * 512 + lane * 8);
    #pragma unroll
    for (int j = 0; j < 4; ++j)
      bf[j] = *reinterpret_cast<const s16x8*>(Bs + (nh + j) * 512 + lane * 8);
    #pragma unroll
    for (int i = 0; i < 4; ++i)
      #pragma unroll
      for (int j = 0; j < 4; ++j)
        acc[i][j] = __builtin_amdgcn_mfma_f32_16x16x32_bf16(af[i], bf[j], acc[i][j], 0, 0, 0);
  }

  // epilogue: gelu -> per-wave LDS transpose -> dense 16B stores
  ushort_t* hbase = Hc + (size_t)blockIdx.y * 128 * FF + nb * 128;
  int m0 = (w & 1) * 64, n0 = (w >> 1) * 64;
  ushort_t* tb = &tbuf[w][0];
  int rowi = lane >> 2, fch = (lane & 3) * 8;
  #pragma unroll
  for (int half = 0; half < 2; ++half) {
    #pragma unroll
    for (int jj = 0; jj < 2; ++jj) {
      int j = half * 2 + jj;
      float bj = b1[e * FF + nb * 128 + n0 + j * 16 + l15];
      #pragma unroll
      for (int i = 0; i < 4; ++i)
        #pragma unroll
        for (int r = 0; r < 4; ++r)
          tb[(i * 16 + q * 4 + r) * 34 + jj * 16 + l15] = f2bf(gelu_f(acc[i][j][r] + bj));
    }
    #pragma unroll
    for (int rr = 0; rr < 4; ++rr) {
      int m_loc = rr * 16 + rowi;
      s16x8 v = *reinterpret_cast<const s16x8*>(tb + m_loc * 34 + fch);
      *reinterpret_cast<s16x8*>(hbase + (size_t)(m0 + m_loc) * FF + n0 + half * 32 + fch) = v;
    }
  }
}

// ---------------------------------------------------------------------------
// GEMM2: y[id][384] = (Hc[m][1536] @ W2t^T + b2) * gate_w.  Same structure.
// ---------------------------------------------------------------------------
__global__ __launch_bounds__(256, 4) void k_gemm2(const ushort_t* __restrict__ Hc,
                                                  const ushort_t* __restrict__ w2t,
                                                  const float* __restrict__ b2,
                                                  const int* __restrict__ basep,
                                                  const int* __restrict__ tile2e,
                                                  const int* __restrict__ gids,
                                                  const float* __restrict__ gwts,
                                                  ushort_t* __restrict__ y, int t0) {
  int g = t0 + blockIdx.y;
  if (g * 128 >= basep[EE]) return;
  int e = tile2e[g], nb = blockIdx.x;
  __shared__ ushort_t As[4096];
  __shared__ ushort_t Bs[4096];
  __shared__ ushort_t tbuf[4][64 * 34];
  __shared__ int   s_id[128];
  __shared__ float s_w[128];
  int t = threadIdx.x, w = t >> 6, lane = t & 63;
  int l15 = lane & 15, q = lane >> 4;
  if (t < 128) {
    s_id[t] = gids[g * 128 + t];
    s_w[t]  = gwts[g * 128 + t];
  }
  const ushort_t* a_src = Hc + (size_t)blockIdx.y * 128 * FF;
  const ushort_t* b_src = w2t + ((size_t)e * CC + nb * 128) * FF;
  int mh = (w & 1) * 4, nh = (w >> 1) * 4;
  f32x4 acc[4][4];
  #pragma unroll
  for (int i = 0; i < 4; ++i)
    #pragma unroll
    for (int j = 0; j < 4; ++j) acc[i][j] = (f32x4){0.f, 0.f, 0.f, 0.f};

  for (int k0 = 0; k0 < FF; k0 += 32) {
    __syncthreads();
    #pragma unroll
    for (int c = 0; c < 2; ++c) {
      int ch = w * 2 + c;
      GLDS(a_src + (size_t)(ch * 16 + l15) * FF + k0 + q * 8, As + ch * 512);
      GLDS(b_src + (size_t)(ch * 16 + l15) * FF + k0 + q * 8, Bs + ch * 512);
    }
    __syncthreads();
    s16x8 af[4], bf[4];
    #pragma unroll
    for (int i = 0; i < 4; ++i)
      af[i] = *reinterpret_cast<const s16x8*>(As + (mh + i) * 512 + lane * 8);
    #pragma unroll
    for (int j = 0; j < 4; ++j)
      bf[j] = *reinterpret_cast<const s16x8*>(Bs + (nh + j) * 512 + lane * 8);
    #pragma unroll
    for (int i = 0; i < 4; ++i)
      #pragma unroll
      for (int j = 0; j < 4; ++j)
        acc[i][j] = __builtin_amdgcn_mfma_f32_16x16x32_bf16(af[i], bf[j], acc[i][j], 0, 0, 0);
  }

  // epilogue: +b2, *gate -> per-wave LDS transpose -> scattered rows, dense 16B
  int m0 = (w & 1) * 64, n0 = (w >> 1) * 64;
  ushort_t* tb = &tbuf[w][0];
  int rowi = lane >> 2, fch = (lane & 3) * 8;
  float wrow[4][4];
  #pragma unroll
  for (int i = 0; i < 4; ++i)
    #pragma unroll
    for (int r = 0; r < 4; ++r) wrow[i][r] = s_w[m0 + i * 16 + q * 4 + r];
  #pragma unroll
  for (int half = 0; half < 2; ++half) {
    #pragma unroll
    for (int jj = 0; jj < 2; ++jj) {
      int j = half * 2 + jj;
      float bj = b2[e * CC + nb * 128 + n0 + j * 16 + l15];
      #pragma unroll
      for (int i = 0; i < 4; ++i)
        #pragma unroll
        for (int r = 0; r < 4; ++r)
          tb[(i * 16 + q * 4 + r) * 34 + jj * 16 + l15] = f2bf((acc[i][j][r] + bj) * wrow[i][r]);
    }
    #pragma unroll
    for (int rr = 0; rr < 4; ++rr) {
      int m_loc = rr * 16 + rowi;
      int id = s_id[m0 + m_loc];
      if (id >= 0) {
        s16x8 v = *reinterpret_cast<const s16x8*>(tb + m_loc * 34 + fch);
        *reinterpret_cast<s16x8*>(y + (size_t)id * CC + nb * 128 + n0 + half * 32 + fch) = v;
      }
    }
  }
}

// ---------------------------------------------------------------------------
// Finalize: out[b][h][c][w] = y[pix] + y[32768+pix]  (bf16 -> f32, transpose)
// ---------------------------------------------------------------------------
__global__ __launch_bounds__(256) void k_final(const ushort_t* __restrict__ y,
                                               float* __restrict__ out) {
  int bid = blockIdx.x;                 // b*64 + h
  __shared__ float tile[64][193];
  int t = threadIdx.x;
  float* dst = out + (size_t)bid * CC * WWID;   // [c][w]
  #pragma unroll
  for (int half = 0; half < 2; ++half) {
    int c0 = half * 192;
    for (int i = t; i < 64 * 48; i += 256) {
      int w = i / 48, c4 = (i % 48) * 4;
      int pix = (bid << 6) + w;
      u16x4 a = *reinterpret_cast<const u16x4*>(y + (size_t)pix * CC + c0 + c4);
      u16x4 b = *reinterpret_cast<const u16x4*>(y + (size_t)(32768 + pix) * CC + c0 + c4);
      #pragma unroll
      for (int k = 0; k < 4; ++k)
        tile[w][c4 + k] = bf2f(a[k]) + bf2f(b[k]);
    }
    __syncthreads();
    for (int i = t; i < 64 * 192; i += 256) {
      int cl = i / 64, w = i % 64;
      dst[(size_t)(c0 + cl) * WWID + w] = tile[w][cl];
    }
    __syncthreads();
  }
}

// ---------------------------------------------------------------------------
extern "C" void kernel_launch(void* const* d_in, const int* in_sizes, int n_in,
                              void* d_out, int out_size, void* d_ws, size_t ws_size,
                              hipStream_t stream) {
  const float* x  = (const float*)d_in[0];
  const float* gw = (const float*)d_in[1];
  const float* w1 = (const float*)d_in[2];
  const float* b1 = (const float*)d_in[3];
  const float* w2 = (const float*)d_in[4];
  const float* b2 = (const float*)d_in[5];

  const size_t fixed = (size_t)EE * FF * CC * 2 * 2   // w1t, w2t
                     + (size_t)65536 * CC * 2          // y
                     + (size_t)MTOTMAX * 4 * 2         // gids,gwts
                     + (size_t)BB * LL * 2 * 4 * 2     // re, rw
                     + (size_t)NTMAX * 4               // tile2e
                     + 1024;
  const int cands[7] = {66560, 32768, 16384, 8192, 4096, 2048, 1024};
  int MC = 1024;
  for (int i = 0; i < 7; ++i)
    if (fixed + (size_t)cands[i] * 3840 <= ws_size) { MC = cands[i]; break; }
  const int npass = (MTOTMAX + MC - 1) / MC;
  const int ntile = MC / 128;

  char* ws = (char*)d_ws;
  size_t off = 0;
  ushort_t* Xc   = (ushort_t*)(ws + off); off += (size_t)MC * CC * 2;
  ushort_t* Hc   = (ushort_t*)(ws + off); off += (size_t)MC * FF * 2;
  ushort_t* w1t  = (ushort_t*)(ws + off); off += (size_t)EE * FF * CC * 2;
  ushort_t* w2t  = (ushort_t*)(ws + off); off += (size_t)EE * FF * CC * 2;
  ushort_t* y    = (ushort_t*)(ws + off); off += (size_t)65536 * CC * 2;
  int*   gids  = (int*)(ws + off);   off += (size_t)MTOTMAX * 4;
  float* gwts  = (float*)(ws + off); off += (size_t)MTOTMAX * 4;
  int*   re    = (int*)(ws + off);   off += (size_t)BB * LL * 2 * 4;
  float* rw    = (float*)(ws + off); off += (size_t)BB * LL * 2 * 4;
  int*   tile2e= (int*)(ws + off);   off += (size_t)NTMAX * 4;
  int*   cnt   = (int*)(ws + off);   off += 64;
  int*   cnt2  = (int*)(ws + off);   off += 64;
  int*   cntp  = (int*)(ws + off);   off += 64;
  int*   basep = (int*)(ws + off);   off += 64;

  hipMemsetAsync(cnt, 0, 128, stream);   // cnt + cnt2

  k_transpose<<<dim3(FF / 32, CC / 32, EE), 256, 0, stream>>>(w1, w1t, CC, FF); // [E][F][C]
  k_transpose<<<dim3(CC / 32, FF / 32, EE), 256, 0, stream>>>(w2, w2t, FF, CC); // [E][C][F]
  k_router<<<BB * LL, 256, 0, stream>>>(x, gw, re, rw, cnt);
  k_pad<<<1, 256, 0, stream>>>(cnt, cntp, basep, tile2e, gids, gwts);
  k_assign<<<16, 256, 0, stream>>>(re, rw, basep, cnt2, gids, gwts);

  for (int p = 0; p < npass; ++p) {
    int t0 = p * ntile;
    k_gather<<<ntile, 256, 0, stream>>>(x, gids, basep, Xc, t0);
    k_gemm1<<<dim3(FF / 128, ntile), 256, 0, stream>>>(Xc, w1t, b1, basep, tile2e, Hc, t0);
    k_gemm2<<<dim3(CC / 128, ntile), 256, 0, stream>>>(Hc, w2t, b2, basep, tile2e, gids, gwts, y, t0);
  }
  k_final<<<BB * HH, 256, 0, stream>>>(y, (float*)d_out);
}